// Round 9
// baseline (132.944 us; speedup 1.0000x reference)
//
#include <hip/hip_runtime.h>

#define SEQ 4096
#define EMB 768
#define NH 12
#define HD 64
#define KDIM 768
#define LNEG -100000000.0f
#define LOG2E 1.44269504f

typedef __attribute__((ext_vector_type(8))) short short8;
typedef __attribute__((ext_vector_type(4))) short short4v;
typedef __attribute__((ext_vector_type(4))) float f32x4;

__device__ inline unsigned short f2bf(float f) {
    unsigned int u = __float_as_uint(f);
    u += 0x7fffu + ((u >> 16) & 1u);
    return (unsigned short)(u >> 16);
}
__device__ inline float bf2f(unsigned short s) {
    unsigned int u = ((unsigned int)s) << 16;
    return __uint_as_float(u);
}

__device__ inline short8 cat8(short4v lo, short4v hi) {
    return __builtin_shufflevector(lo, hi, 0, 1, 2, 3, 4, 5, 6, 7);
}

__device__ inline void gload_lds16(const unsigned short* g, unsigned short* l) {
    __builtin_amdgcn_global_load_lds(
        (const __attribute__((address_space(1))) void*)g,
        (__attribute__((address_space(3))) void*)l, 16, 0, 0);
}

// ---------------- Prep: hid -> bf16, W -> W^T bf16 (q-scale*log2e folded into Wq) ----------------
__global__ __launch_bounds__(256) void prep_kernel(
    const float* __restrict__ hid,
    const float* __restrict__ Wq, const float* __restrict__ Wk, const float* __restrict__ Wv,
    unsigned short* __restrict__ hidb,   // [4096][768] bf16
    unsigned short* __restrict__ Wt)     // [2304][768] bf16, [n][k]
{
    const int bid = blockIdx.x;
    const int t = threadIdx.x;
    if (bid >= 432) {
        int vid = (bid - 432) * 256 + t;
        const int nch = SEQ * EMB / 4;
        const int stride = 576 * 256;
        for (int c = vid; c < nch; c += stride) {
            f32x4 v = ((const f32x4*)hid)[c];
            short4v o;
            #pragma unroll
            for (int x = 0; x < 4; x++) o[x] = (short)f2bf(v[x]);
            ((short4v*)hidb)[c] = o;
        }
        return;
    }
    const int mat = bid / 144;
    const int r2 = bid % 144;
    const int k0 = (r2 % 12) * 64;
    const int n0 = (r2 / 12) * 64;
    const float* Wm = (mat == 0) ? Wq : (mat == 1 ? Wk : Wv);
    const float scale = (mat == 0) ? 0.125f * LOG2E : 1.0f;
    __shared__ unsigned short Lt[64 * 82];
    #pragma unroll
    for (int i = 0; i < 4; i++) {
        int row = i * 16 + (t >> 4);
        int col = (t & 15) * 4;
        f32x4 v = *(const f32x4*)(Wm + (size_t)(k0 + row) * EMB + n0 + col);
        #pragma unroll
        for (int x = 0; x < 4; x++)
            Lt[(col + x) * 82 + row] = f2bf(v[x] * scale);
    }
    __syncthreads();
    #pragma unroll
    for (int j = 0; j < 2; j++) {
        int idx = j * 256 + t;
        int nr = idx >> 3;
        int kc = (idx & 7) * 8;
        short8 o = *(const short8*)(Lt + nr * 82 + kc);
        *(short8*)(Wt + (size_t)(mat * 768 + n0 + nr) * KDIM + k0 + kc) = o;
    }
}

// ---------------- GEMM R8: 128x128 tile, 512 thr / 8 waves (2x4), grid (32,18) ----------------
// Budget subtraction (R0/R4, attn measured directly): gemm ~= 50 us = 290 TF,
// the largest controllable block. R6's 128x128 failure re-diagnosed as per-wave
// register pressure (acc[4][4]=64 VGPR + frags at 256 thr), not tile size.
// This version keeps R5's PROVEN per-wave schedule and register shape exactly
// (acc[4][2], 12 ds_read_b128 + 16 MFMA per k-step) and maps 8 waves (2 row x
// 4 col) onto the 128x128 tile: per-output staging traffic halves (A 18x,
// B 32x re-read = 226 MB vs R5's 340 MB), per-thread gloads 6 -> 4 per k-step.
__global__ __launch_bounds__(512) void gemm_kernel(
    const unsigned short* __restrict__ hidb,
    const unsigned short* __restrict__ Wt,
    const float* __restrict__ bq, const float* __restrict__ bk, const float* __restrict__ bv,
    unsigned short* __restrict__ q_ws,   // [H][S][D] bf16
    unsigned short* __restrict__ k_ws,   // [H][S][D] bf16
    unsigned short* __restrict__ v_ws)   // [H][D][S] bf16
{
    const int m0 = blockIdx.x * 128;
    const int n0 = blockIdx.y * 128;
    __shared__ union {
        struct { unsigned short Al[128 * 64]; unsigned short Bl[128 * 64]; } s;  // 32 KB
        unsigned short Cqk[128 * 136];   // 34.8 KB
        unsigned short Cv[128 * 136];    // 34.8 KB
    } sm;
    const int t = threadIdx.x;
    const int wave = t >> 6, lane = t & 63;
    const int quad = lane >> 4, l16 = lane & 15;
    const int wm = wave >> 2, wn = wave & 3;    // 2x4 wave grid: 64 rows x 32 cols per wave

    const f32x4 zero = {0.f, 0.f, 0.f, 0.f};
    f32x4 acc[4][2];
    #pragma unroll
    for (int i = 0; i < 4; i++)
        #pragma unroll
        for (int j = 0; j < 2; j++) acc[i][j] = zero;

    for (int k0 = 0; k0 < KDIM; k0 += 64) {
        #pragma unroll
        for (int i = 0; i < 2; i++) {
            int c = (wave * 2 + i) * 64 + lane;           // 1024 granules
            int row = c >> 3;
            int kc = ((c & 7) ^ (row & 7)) * 8;
            gload_lds16(hidb + (size_t)(m0 + row) * KDIM + k0 + kc, sm.s.Al + (wave * 2 + i) * 512);
        }
        #pragma unroll
        for (int i = 0; i < 2; i++) {
            int c = (wave * 2 + i) * 64 + lane;
            int row = c >> 3;
            int kc = ((c & 7) ^ (row & 7)) * 8;
            gload_lds16(Wt + (size_t)(n0 + row) * KDIM + k0 + kc, sm.s.Bl + (wave * 2 + i) * 512);
        }
        __syncthreads();

        short8 af[2][4], bfr[2][2];
        #pragma unroll
        for (int rt = 0; rt < 4; rt++) {
            int rowA = wm * 64 + rt * 16 + l16;
            #pragma unroll
            for (int s = 0; s < 2; s++)
                af[s][rt] = *(const short8*)(sm.s.Al + rowA * 64 + (((s << 2) | quad) ^ (rowA & 7)) * 8);
        }
        #pragma unroll
        for (int ct = 0; ct < 2; ct++) {
            int rowB = wn * 32 + ct * 16 + l16;
            #pragma unroll
            for (int s = 0; s < 2; s++)
                bfr[s][ct] = *(const short8*)(sm.s.Bl + rowB * 64 + (((s << 2) | quad) ^ (rowB & 7)) * 8);
        }
        #pragma unroll
        for (int s = 0; s < 2; s++)
            #pragma unroll
            for (int rt = 0; rt < 4; rt++)
                #pragma unroll
                for (int ct = 0; ct < 2; ct++)
                    acc[rt][ct] = __builtin_amdgcn_mfma_f32_16x16x32_bf16(af[s][rt], bfr[s][ct], acc[rt][ct], 0, 0, 0);
        __syncthreads();
    }

    const int mat = blockIdx.y / 6;
    const float* bm = (mat == 0) ? bq : (mat == 1 ? bk : bv);
    const float bscale = (mat == 0) ? 0.125f * LOG2E : 1.0f;

    if (mat != 2) {
        #pragma unroll
        for (int ct = 0; ct < 2; ct++) {
            int nloc = wn * 32 + ct * 16 + l16;
            float bias = bm[(n0 + nloc) - mat * 768] * bscale;
            #pragma unroll
            for (int rt = 0; rt < 4; rt++)
                #pragma unroll
                for (int r = 0; r < 4; r++)
                    sm.Cqk[(wm * 64 + rt * 16 + quad * 4 + r) * 136 + nloc] = f2bf(acc[rt][ct][r] + bias);
        }
        __syncthreads();
        unsigned short* dst_ws = (mat == 0) ? q_ws : k_ws;
        #pragma unroll
        for (int p = 0; p < 4; p++) {
            int id = p * 512 + t;            // 2048 = 128 rows x 16 chunks
            int row = id >> 4, nc = id & 15;
            short8 val = *(const short8*)(sm.Cqk + row * 136 + nc * 8);
            int within = (n0 + nc * 8) - mat * 768;
            int head = within >> 6, dd = within & 63;
            *(short8*)(dst_ws + (size_t)head * (SEQ * HD) + (size_t)(m0 + row) * HD + dd) = val;
        }
    } else {
        #pragma unroll
        for (int ct = 0; ct < 2; ct++) {
            int nloc = wn * 32 + ct * 16 + l16;
            float bias = bm[(n0 + nloc) - 1536];
            #pragma unroll
            for (int rt = 0; rt < 4; rt++)
                #pragma unroll
                for (int r = 0; r < 4; r++)
                    sm.Cv[nloc * 136 + wm * 64 + rt * 16 + quad * 4 + r] = f2bf(acc[rt][ct][r] + bias);
        }
        __syncthreads();
        #pragma unroll
        for (int p = 0; p < 4; p++) {
            int id = p * 512 + t;            // 2048 = 128 dd x 16 chunks
            int ddl = id >> 4;
            int sseg = (id & 15) * 8;
            short8 val = *(const short8*)(sm.Cv + ddl * 136 + sseg);
            int within = (n0 + ddl) - 1536;
            int head = within >> 6, dd = within & 63;
            *(short8*)(v_ws + (size_t)head * (HD * SEQ) + (size_t)dd * SEQ + m0 + sseg) = val;
        }
    }
}

// ---------------- Banded attention R7: 64 rows/WG x 768 WGs (unchanged) ----------------
__global__ __launch_bounds__(256, 3) void attn_kernel(
    const unsigned short* __restrict__ q_ws,
    const unsigned short* __restrict__ k_ws,
    const unsigned short* __restrict__ v_ws,
    const float* __restrict__ amask,
    const unsigned char* __restrict__ imask,
    float* __restrict__ out)
{
    const int lbid = blockIdx.x;                  // 768 = 8 XCD * 96
    const int xcd = lbid & 7, slot = lbid >> 3;
    const int wg = xcd * 96 + slot;               // bijective (768 % 8 == 0)
    const int h = wg >> 6, c64 = wg & 63;
    const int i0 = c64 * 64;
    const int t = threadIdx.x;
    const int wave = t >> 6, lane = t & 63;
    const int quad = lane >> 4, l16 = lane & 15;
    const int rowoff = wave * 16 + l16;           // 0..63
    const int row_g = i0 + rowoff;

    __shared__ unsigned short Ksh[2][64 * 72];    // [key][dd], stride 72
    __shared__ unsigned short Vsh[2][64 * 72];    // [dd][key], stride 72
    __shared__ float fm[576];                     // per-key mask (log2 domain)

    const int jw = i0 - 256;                      // WG key-window origin
    for (int cc = t; cc < 576; cc += 256) {
        int j = jw + cc;
        fm[cc] = ((unsigned)j >= SEQ) ? -1e30f : ((amask[j] != 0.0f) ? LNEG * LOG2E : 0.0f);
    }

    // staging: 2 K granules + 2 V granules per thread per chunk (512 granules each)
    const int kr0 = t >> 3,        kc0 = (t & 7) * 8;          // granule t
    const int kr1 = (t + 256) >> 3, kc1 = (t & 7) * 8;         // granule t+256
    const unsigned short* kh = k_ws + h * (SEQ * HD);
    const unsigned short* vh = v_ws + h * (HD * SEQ);

    // stage chunk 0 directly
    {
        int a0i = min(max(jw + kr0, 0), SEQ - 1);
        int a1i = min(max(jw + kr1, 0), SEQ - 1);
        *(short8*)(&Ksh[0][kr0 * 72 + kc0]) = *(const short8*)(kh + (size_t)a0i * HD + kc0);
        *(short8*)(&Ksh[0][kr1 * 72 + kc1]) = *(const short8*)(kh + (size_t)a1i * HD + kc1);
        int b0i = min(max(jw + kc0, 0), SEQ - 8);
        int b1i = min(max(jw + kc1, 0), SEQ - 8);
        *(short8*)(&Vsh[0][kr0 * 72 + kc0]) = *(const short8*)(vh + (size_t)kr0 * SEQ + b0i);
        *(short8*)(&Vsh[0][kr1 * 72 + kc1]) = *(const short8*)(vh + (size_t)kr1 * SEQ + b1i);
    }
    // preload chunk 1 into registers (T14: issue early, write late)
    short8 kA, kB, vA, vB;
    {
        int a0i = min(max(jw + 64 + kr0, 0), SEQ - 1);
        int a1i = min(max(jw + 64 + kr1, 0), SEQ - 1);
        kA = *(const short8*)(kh + (size_t)a0i * HD + kc0);
        kB = *(const short8*)(kh + (size_t)a1i * HD + kc1);
        int b0i = min(max(jw + 64 + kc0, 0), SEQ - 8);
        int b1i = min(max(jw + 64 + kc1, 0), SEQ - 8);
        vA = *(const short8*)(vh + (size_t)kr0 * SEQ + b0i);
        vB = *(const short8*)(vh + (size_t)kr1 * SEQ + b1i);
    }

    // Q fragment (B-operand): col = qrow, k = dd
    const unsigned short* qb = q_ws + h * (SEQ * HD) + (size_t)row_g * HD + quad * 8;
    short8 a0 = *(const short8*)qb;
    short8 a1 = *(const short8*)(qb + 32);

    const f32x4 zero = {0.f, 0.f, 0.f, 0.f};
    f32x4 acc0 = zero, acc1 = zero, acc2 = zero, acc3 = zero;
    float sum = 0.f;

    for (int c = 0; c < 9; ++c) {
        __syncthreads();   // staged chunk c visible to all waves
        const unsigned short* Kb = Ksh[c & 1];
        const unsigned short* Vb = Vsh[c & 1];

        // ---- S^T: 4 key-tiles of 16; A = K[key][dd] from LDS, B = Q ----
        f32x4 st[4];
        #pragma unroll
        for (int tt = 0; tt < 4; ++tt) {
            const unsigned short* kp = Kb + (tt * 16 + l16) * 72 + quad * 8;
            short8 kf0 = *(const short8*)kp;
            short8 kf1 = *(const short8*)(kp + 32);
            f32x4 s = zero;
            s = __builtin_amdgcn_mfma_f32_16x16x32_bf16(kf0, a0, s, 0, 0, 0);
            s = __builtin_amdgcn_mfma_f32_16x16x32_bf16(kf1, a1, s, 0, 0, 0);
            st[tt] = s;
        }

        // ---- mask + exp2 + RNE-bf16 + row-sum (P stays in registers) ----
        unsigned short pb[16];
        #pragma unroll
        for (int tt = 0; tt < 4; ++tt) {
            f32x4 fmv = *(const f32x4*)(fm + 64 * c + 16 * tt + 4 * quad);
            #pragma unroll
            for (int r = 0; r < 4; ++r) {
                int cc = 64 * c + 16 * tt + 4 * quad + r;
                float arg = ((unsigned)(cc - rowoff) <= 512u) ? (st[tt][r] + fmv[r]) : -1e30f;
                unsigned short p = f2bf(__builtin_amdgcn_exp2f(arg));
                pb[tt * 4 + r] = p;
                sum += bf2f(p);
            }
        }

        // ---- PV: 2 key-groups of 32; A = V^T[dd][key] from LDS, B = packed P ----
        #pragma unroll
        for (int u = 0; u < 2; ++u) {
            union { unsigned int uu[4]; short8 s8; } pf;
            pf.uu[0] = (unsigned int)pb[8 * u + 0] | ((unsigned int)pb[8 * u + 1] << 16);
            pf.uu[1] = (unsigned int)pb[8 * u + 2] | ((unsigned int)pb[8 * u + 3] << 16);
            pf.uu[2] = (unsigned int)pb[8 * u + 4] | ((unsigned int)pb[8 * u + 5] << 16);
            pf.uu[3] = (unsigned int)pb[8 * u + 6] | ((unsigned int)pb[8 * u + 7] << 16);
            const unsigned short* vp0 = Vb + l16 * 72 + u * 32 + quad * 4;
            short4v v00 = *(const short4v*)(vp0);
            short4v v01 = *(const short4v*)(vp0 + 16);
            acc0 = __builtin_amdgcn_mfma_f32_16x16x32_bf16(cat8(v00, v01), pf.s8, acc0, 0, 0, 0);
            const unsigned short* vp1 = vp0 + 16 * 72;
            short4v v10 = *(const short4v*)(vp1);
            short4v v11 = *(const short4v*)(vp1 + 16);
            acc1 = __builtin_amdgcn_mfma_f32_16x16x32_bf16(cat8(v10, v11), pf.s8, acc1, 0, 0, 0);
            const unsigned short* vp2 = vp0 + 32 * 72;
            short4v v20 = *(const short4v*)(vp2);
            short4v v21 = *(const short4v*)(vp2 + 16);
            acc2 = __builtin_amdgcn_mfma_f32_16x16x32_bf16(cat8(v20, v21), pf.s8, acc2, 0, 0, 0);
            const unsigned short* vp3 = vp0 + 48 * 72;
            short4v v30 = *(const short4v*)(vp3);
            short4v v31 = *(const short4v*)(vp3 + 16);
            acc3 = __builtin_amdgcn_mfma_f32_16x16x32_bf16(cat8(v30, v31), pf.s8, acc3, 0, 0, 0);
        }

        // ---- stage chunk c+1 (other buffer; barrier-separated: race-free) ----
        if (c < 8) {
            *(short8*)(&Ksh[(c + 1) & 1][kr0 * 72 + kc0]) = kA;
            *(short8*)(&Ksh[(c + 1) & 1][kr1 * 72 + kc1]) = kB;
            *(short8*)(&Vsh[(c + 1) & 1][kr0 * 72 + kc0]) = vA;
            *(short8*)(&Vsh[(c + 1) & 1][kr1 * 72 + kc1]) = vB;
            if (c < 7) {
                int base = jw + 64 * (c + 2);
                int a0i = min(max(base + kr0, 0), SEQ - 1);
                int a1i = min(max(base + kr1, 0), SEQ - 1);
                kA = *(const short8*)(kh + (size_t)a0i * HD + kc0);
                kB = *(const short8*)(kh + (size_t)a1i * HD + kc1);
                int b0i = min(max(base + kc0, 0), SEQ - 8);
                int b1i = min(max(base + kc1, 0), SEQ - 8);
                vA = *(const short8*)(vh + (size_t)kr0 * SEQ + b0i);
                vB = *(const short8*)(vh + (size_t)kr1 * SEQ + b1i);
            }
        }
    }

    // ---- row-sum across quads (lanes sharing l16), normalize, write O^T ----
    sum += __shfl_xor(sum, 16);
    sum += __shfl_xor(sum, 32);
    float rinv = imask[row_g] ? 0.f : __builtin_amdgcn_rcpf(sum);

    float* ob = out + (size_t)row_g * EMB + h * HD + quad * 4;
    f32x4 o;
    #pragma unroll
    for (int r = 0; r < 4; ++r) o[r] = acc0[r] * rinv;
    *(f32x4*)(ob) = o;
    #pragma unroll
    for (int r = 0; r < 4; ++r) o[r] = acc1[r] * rinv;
    *(f32x4*)(ob + 16) = o;
    #pragma unroll
    for (int r = 0; r < 4; ++r) o[r] = acc2[r] * rinv;
    *(f32x4*)(ob + 32) = o;
    #pragma unroll
    for (int r = 0; r < 4; ++r) o[r] = acc3[r] * rinv;
    *(f32x4*)(ob + 48) = o;
}

extern "C" void kernel_launch(void* const* d_in, const int* in_sizes, int n_in,
                              void* d_out, int out_size, void* d_ws, size_t ws_size,
                              hipStream_t stream) {
    (void)in_sizes; (void)n_in; (void)out_size; (void)ws_size;
    const float* hid = (const float*)d_in[0];
    const float* am  = (const float*)d_in[1];
    const unsigned char* im = (const unsigned char*)d_in[2];
    const float* Wq = (const float*)d_in[3];
    const float* bq = (const float*)d_in[4];
    const float* Wk = (const float*)d_in[5];
    const float* bk = (const float*)d_in[6];
    const float* Wv = (const float*)d_in[7];
    const float* bv = (const float*)d_in[8];
    float* out = (float*)d_out;

    unsigned short* ws = (unsigned short*)d_ws;
    unsigned short* q_ws = ws;
    unsigned short* k_ws = ws + (size_t)NH * SEQ * HD;
    unsigned short* v_ws = ws + 2 * (size_t)NH * SEQ * HD;
    unsigned short* hidb = (unsigned short*)d_out;   // d_out as scratch (attn overwrites last)
    unsigned short* Wt   = hidb + (size_t)SEQ * EMB;

    prep_kernel<<<dim3(1008), 256, 0, stream>>>(hid, Wq, Wk, Wv, hidb, Wt);
    gemm_kernel<<<dim3(32, 18), 512, 0, stream>>>(hidb, Wt, bq, bk, bv, q_ws, k_ws, v_ws);
    attn_kernel<<<dim3(768), 256, 0, stream>>>(q_ws, k_ws, v_ws, am, im, out);
}

// Round 10
// 125.819 us; speedup vs baseline: 1.0566x; 1.0566x over previous
//
#include <hip/hip_runtime.h>

#define SEQ 4096
#define EMB 768
#define NH 12
#define HD 64
#define KDIM 768
#define LNEG -100000000.0f
#define LOG2E 1.44269504f

typedef __attribute__((ext_vector_type(8))) short short8;
typedef __attribute__((ext_vector_type(4))) short short4v;
typedef __attribute__((ext_vector_type(4))) float f32x4;

__device__ inline unsigned short f2bf(float f) {
    unsigned int u = __float_as_uint(f);
    u += 0x7fffu + ((u >> 16) & 1u);
    return (unsigned short)(u >> 16);
}
__device__ inline float bf2f(unsigned short s) {
    unsigned int u = ((unsigned int)s) << 16;
    return __uint_as_float(u);
}

__device__ inline short8 cat8(short4v lo, short4v hi) {
    return __builtin_shufflevector(lo, hi, 0, 1, 2, 3, 4, 5, 6, 7);
}

__device__ inline void gload_lds16(const unsigned short* g, unsigned short* l) {
    __builtin_amdgcn_global_load_lds(
        (const __attribute__((address_space(1))) void*)g,
        (__attribute__((address_space(3))) void*)l, 16, 0, 0);
}

// ---------------- Prep: hid -> bf16, W -> W^T bf16 (q-scale*log2e folded into Wq) ----------------
__global__ __launch_bounds__(256) void prep_kernel(
    const float* __restrict__ hid,
    const float* __restrict__ Wq, const float* __restrict__ Wk, const float* __restrict__ Wv,
    unsigned short* __restrict__ hidb,   // [4096][768] bf16
    unsigned short* __restrict__ Wt)     // [2304][768] bf16, [n][k]
{
    const int bid = blockIdx.x;
    const int t = threadIdx.x;
    if (bid >= 432) {
        int vid = (bid - 432) * 256 + t;
        const int nch = SEQ * EMB / 4;
        const int stride = 576 * 256;
        for (int c = vid; c < nch; c += stride) {
            f32x4 v = ((const f32x4*)hid)[c];
            short4v o;
            #pragma unroll
            for (int x = 0; x < 4; x++) o[x] = (short)f2bf(v[x]);
            ((short4v*)hidb)[c] = o;
        }
        return;
    }
    const int mat = bid / 144;
    const int r2 = bid % 144;
    const int k0 = (r2 % 12) * 64;
    const int n0 = (r2 / 12) * 64;
    const float* Wm = (mat == 0) ? Wq : (mat == 1 ? Wk : Wv);
    const float scale = (mat == 0) ? 0.125f * LOG2E : 1.0f;
    __shared__ unsigned short Lt[64 * 82];
    #pragma unroll
    for (int i = 0; i < 4; i++) {
        int row = i * 16 + (t >> 4);
        int col = (t & 15) * 4;
        f32x4 v = *(const f32x4*)(Wm + (size_t)(k0 + row) * EMB + n0 + col);
        #pragma unroll
        for (int x = 0; x < 4; x++)
            Lt[(col + x) * 82 + row] = f2bf(v[x] * scale);
    }
    __syncthreads();
    #pragma unroll
    for (int j = 0; j < 2; j++) {
        int idx = j * 256 + t;
        int nr = idx >> 3;
        int kc = (idx & 7) * 8;
        short8 o = *(const short8*)(Lt + nr * 82 + kc);
        *(short8*)(Wt + (size_t)(mat * 768 + n0 + nr) * KDIM + k0 + kc) = o;
    }
}

// ---------------- GEMM R10: 64x128 tile + 2-phase counted-vmcnt pipeline ----------------
// R6/R9 tile-geometry moves both failed (+11/+2 us) -> geometry is not the
// bottleneck. Remaining structural difference vs the m97 ladder class: K=768
// gives only 12 k-steps, and the old loop exposed the full stage->drain
// latency every step (__syncthreads lowers to s_waitcnt vmcnt(0) lgkmcnt(0)).
// T3/T4-minimal fix: double-buffered staging; issue tile t+1's 6 gloads FIRST,
// then vmcnt(6) (counted: only tile t's 6 oldest must retire, m135 semantics)
// + raw s_barrier, compute tile t, raw s_barrier with NO waitcnt so t+1's
// loads fly across it. sched_barrier(0) pins the asm (rule #18). Race-audit:
// STAGE into buf b at t+1 only after the t-end barrier proves all ds_reads of
// b retired; consumer waits own vmcnt then barrier. LDS 48 KB -> 3 WGs/CU.
__global__ __launch_bounds__(256) void gemm_kernel(
    const unsigned short* __restrict__ hidb,
    const unsigned short* __restrict__ Wt,
    const float* __restrict__ bq, const float* __restrict__ bk, const float* __restrict__ bv,
    unsigned short* __restrict__ q_ws,   // [H][S][D] bf16
    unsigned short* __restrict__ k_ws,   // [H][S][D] bf16
    unsigned short* __restrict__ v_ws)   // [H][D][S] bf16
{
    const int m0 = blockIdx.x * 64;
    const int n0 = blockIdx.y * 128;
    __shared__ union {
        struct { unsigned short Al[2][64 * 64]; unsigned short Bl[2][128 * 64]; } s;  // 48 KB
        unsigned short Cqk[64 * 136];   // 17.4 KB
        unsigned short Cv[128 * 72];    // 18.4 KB
    } sm;
    const int t = threadIdx.x;
    const int wave = t >> 6, lane = t & 63;
    const int quad = lane >> 4, l16 = lane & 15;

    const f32x4 zero = {0.f, 0.f, 0.f, 0.f};
    f32x4 acc[4][2];
    #pragma unroll
    for (int i = 0; i < 4; i++)
        #pragma unroll
        for (int j = 0; j < 2; j++) acc[i][j] = zero;

    // per-thread staging indices (hoisted out of the loop; wave-uniform LDS dst)
    #define STAGE_AB(bbuf, kk0)                                                            \
    {                                                                                      \
        _Pragma("unroll")                                                                  \
        for (int i = 0; i < 2; i++) {                                                      \
            int c = (wave * 2 + i) * 64 + lane;                                            \
            int row = c >> 3;                                                              \
            int kc = ((c & 7) ^ (row & 7)) * 8;                                            \
            gload_lds16(hidb + (size_t)(m0 + row) * KDIM + (kk0) + kc,                     \
                        sm.s.Al[bbuf] + (wave * 2 + i) * 512);                             \
        }                                                                                  \
        _Pragma("unroll")                                                                  \
        for (int i = 0; i < 4; i++) {                                                      \
            int c = (wave * 4 + i) * 64 + lane;                                            \
            int row = c >> 3;                                                              \
            int kc = ((c & 7) ^ (row & 7)) * 8;                                            \
            gload_lds16(Wt + (size_t)(n0 + row) * KDIM + (kk0) + kc,                       \
                        sm.s.Bl[bbuf] + (wave * 4 + i) * 512);                             \
        }                                                                                  \
    }

    STAGE_AB(0, 0);

    #pragma unroll
    for (int tt = 0; tt < 12; ++tt) {
        if (tt < 11) STAGE_AB((tt + 1) & 1, (tt + 1) * 64);
        __builtin_amdgcn_sched_barrier(0);
        if (tt < 11) asm volatile("s_waitcnt vmcnt(6)" ::: "memory");
        else         asm volatile("s_waitcnt vmcnt(0)" ::: "memory");
        __builtin_amdgcn_sched_barrier(0);
        __builtin_amdgcn_s_barrier();
        __builtin_amdgcn_sched_barrier(0);

        const unsigned short* Acur = sm.s.Al[tt & 1];
        const unsigned short* Bcur = sm.s.Bl[tt & 1];
        short8 af[2][4], bfr[2][2];
        #pragma unroll
        for (int rt = 0; rt < 4; rt++) {
            int rowA = rt * 16 + l16;
            #pragma unroll
            for (int s = 0; s < 2; s++)
                af[s][rt] = *(const short8*)(Acur + rowA * 64 + (((s << 2) | quad) ^ (rowA & 7)) * 8);
        }
        #pragma unroll
        for (int ct = 0; ct < 2; ct++) {
            int rowB = wave * 32 + ct * 16 + l16;
            #pragma unroll
            for (int s = 0; s < 2; s++)
                bfr[s][ct] = *(const short8*)(Bcur + rowB * 64 + (((s << 2) | quad) ^ (rowB & 7)) * 8);
        }
        #pragma unroll
        for (int s = 0; s < 2; s++)
            #pragma unroll
            for (int rt = 0; rt < 4; rt++)
                #pragma unroll
                for (int ct = 0; ct < 2; ct++)
                    acc[rt][ct] = __builtin_amdgcn_mfma_f32_16x16x32_bf16(af[s][rt], bfr[s][ct], acc[rt][ct], 0, 0, 0);

        __builtin_amdgcn_sched_barrier(0);
        __builtin_amdgcn_s_barrier();   // no waitcnt: next tile's loads stay in flight
        __builtin_amdgcn_sched_barrier(0);
    }
    #undef STAGE_AB

    const int mat = blockIdx.y / 6;
    const float* bm = (mat == 0) ? bq : (mat == 1 ? bk : bv);
    const float bscale = (mat == 0) ? 0.125f * LOG2E : 1.0f;

    if (mat != 2) {
        #pragma unroll
        for (int ct = 0; ct < 2; ct++) {
            int nloc = wave * 32 + ct * 16 + l16;
            float bias = bm[(n0 + nloc) - mat * 768] * bscale;
            #pragma unroll
            for (int rt = 0; rt < 4; rt++)
                #pragma unroll
                for (int r = 0; r < 4; r++)
                    sm.Cqk[(rt * 16 + quad * 4 + r) * 136 + nloc] = f2bf(acc[rt][ct][r] + bias);
        }
        __syncthreads();
        unsigned short* dst_ws = (mat == 0) ? q_ws : k_ws;
        #pragma unroll
        for (int p = 0; p < 4; p++) {
            int id = p * 256 + t;            // 1024 = 64 rows x 16 chunks
            int row = id >> 4, nc = id & 15;
            short8 val = *(const short8*)(sm.Cqk + row * 136 + nc * 8);
            int within = (n0 + nc * 8) - mat * 768;
            int head = within >> 6, dd = within & 63;
            *(short8*)(dst_ws + (size_t)head * (SEQ * HD) + (size_t)(m0 + row) * HD + dd) = val;
        }
    } else {
        #pragma unroll
        for (int ct = 0; ct < 2; ct++) {
            int nloc = wave * 32 + ct * 16 + l16;
            float bias = bm[(n0 + nloc) - 1536];
            #pragma unroll
            for (int rt = 0; rt < 4; rt++)
                #pragma unroll
                for (int r = 0; r < 4; r++)
                    sm.Cv[nloc * 72 + rt * 16 + quad * 4 + r] = f2bf(acc[rt][ct][r] + bias);
        }
        __syncthreads();
        #pragma unroll
        for (int p = 0; p < 4; p++) {
            int id = p * 256 + t;            // 1024 = 128 dd x 8 chunks
            int ddl = id >> 3;
            int sseg = (id & 7) * 8;
            short8 val = *(const short8*)(sm.Cv + ddl * 72 + sseg);
            int within = (n0 + ddl) - 1536;
            int head = within >> 6, dd = within & 63;
            *(short8*)(v_ws + (size_t)head * (HD * SEQ) + (size_t)dd * SEQ + m0 + sseg) = val;
        }
    }
}

// ---------------- Banded attention R7: 64 rows/WG x 768 WGs (unchanged) ----------------
__global__ __launch_bounds__(256, 3) void attn_kernel(
    const unsigned short* __restrict__ q_ws,
    const unsigned short* __restrict__ k_ws,
    const unsigned short* __restrict__ v_ws,
    const float* __restrict__ amask,
    const unsigned char* __restrict__ imask,
    float* __restrict__ out)
{
    const int lbid = blockIdx.x;                  // 768 = 8 XCD * 96
    const int xcd = lbid & 7, slot = lbid >> 3;
    const int wg = xcd * 96 + slot;               // bijective (768 % 8 == 0)
    const int h = wg >> 6, c64 = wg & 63;
    const int i0 = c64 * 64;
    const int t = threadIdx.x;
    const int wave = t >> 6, lane = t & 63;
    const int quad = lane >> 4, l16 = lane & 15;
    const int rowoff = wave * 16 + l16;           // 0..63
    const int row_g = i0 + rowoff;

    __shared__ unsigned short Ksh[2][64 * 72];    // [key][dd], stride 72
    __shared__ unsigned short Vsh[2][64 * 72];    // [dd][key], stride 72
    __shared__ float fm[576];                     // per-key mask (log2 domain)

    const int jw = i0 - 256;                      // WG key-window origin
    for (int cc = t; cc < 576; cc += 256) {
        int j = jw + cc;
        fm[cc] = ((unsigned)j >= SEQ) ? -1e30f : ((amask[j] != 0.0f) ? LNEG * LOG2E : 0.0f);
    }

    // staging: 2 K granules + 2 V granules per thread per chunk (512 granules each)
    const int kr0 = t >> 3,        kc0 = (t & 7) * 8;          // granule t
    const int kr1 = (t + 256) >> 3, kc1 = (t & 7) * 8;         // granule t+256
    const unsigned short* kh = k_ws + h * (SEQ * HD);
    const unsigned short* vh = v_ws + h * (HD * SEQ);

    // stage chunk 0 directly
    {
        int a0i = min(max(jw + kr0, 0), SEQ - 1);
        int a1i = min(max(jw + kr1, 0), SEQ - 1);
        *(short8*)(&Ksh[0][kr0 * 72 + kc0]) = *(const short8*)(kh + (size_t)a0i * HD + kc0);
        *(short8*)(&Ksh[0][kr1 * 72 + kc1]) = *(const short8*)(kh + (size_t)a1i * HD + kc1);
        int b0i = min(max(jw + kc0, 0), SEQ - 8);
        int b1i = min(max(jw + kc1, 0), SEQ - 8);
        *(short8*)(&Vsh[0][kr0 * 72 + kc0]) = *(const short8*)(vh + (size_t)kr0 * SEQ + b0i);
        *(short8*)(&Vsh[0][kr1 * 72 + kc1]) = *(const short8*)(vh + (size_t)kr1 * SEQ + b1i);
    }
    // preload chunk 1 into registers (T14: issue early, write late)
    short8 kA, kB, vA, vB;
    {
        int a0i = min(max(jw + 64 + kr0, 0), SEQ - 1);
        int a1i = min(max(jw + 64 + kr1, 0), SEQ - 1);
        kA = *(const short8*)(kh + (size_t)a0i * HD + kc0);
        kB = *(const short8*)(kh + (size_t)a1i * HD + kc1);
        int b0i = min(max(jw + 64 + kc0, 0), SEQ - 8);
        int b1i = min(max(jw + 64 + kc1, 0), SEQ - 8);
        vA = *(const short8*)(vh + (size_t)kr0 * SEQ + b0i);
        vB = *(const short8*)(vh + (size_t)kr1 * SEQ + b1i);
    }

    // Q fragment (B-operand): col = qrow, k = dd
    const unsigned short* qb = q_ws + h * (SEQ * HD) + (size_t)row_g * HD + quad * 8;
    short8 a0 = *(const short8*)qb;
    short8 a1 = *(const short8*)(qb + 32);

    const f32x4 zero = {0.f, 0.f, 0.f, 0.f};
    f32x4 acc0 = zero, acc1 = zero, acc2 = zero, acc3 = zero;
    float sum = 0.f;

    for (int c = 0; c < 9; ++c) {
        __syncthreads();   // staged chunk c visible to all waves
        const unsigned short* Kb = Ksh[c & 1];
        const unsigned short* Vb = Vsh[c & 1];

        // ---- S^T: 4 key-tiles of 16; A = K[key][dd] from LDS, B = Q ----
        f32x4 st[4];
        #pragma unroll
        for (int tt = 0; tt < 4; ++tt) {
            const unsigned short* kp = Kb + (tt * 16 + l16) * 72 + quad * 8;
            short8 kf0 = *(const short8*)kp;
            short8 kf1 = *(const short8*)(kp + 32);
            f32x4 s = zero;
            s = __builtin_amdgcn_mfma_f32_16x16x32_bf16(kf0, a0, s, 0, 0, 0);
            s = __builtin_amdgcn_mfma_f32_16x16x32_bf16(kf1, a1, s, 0, 0, 0);
            st[tt] = s;
        }

        // ---- mask + exp2 + RNE-bf16 + row-sum (P stays in registers) ----
        unsigned short pb[16];
        #pragma unroll
        for (int tt = 0; tt < 4; ++tt) {
            f32x4 fmv = *(const f32x4*)(fm + 64 * c + 16 * tt + 4 * quad);
            #pragma unroll
            for (int r = 0; r < 4; ++r) {
                int cc = 64 * c + 16 * tt + 4 * quad + r;
                float arg = ((unsigned)(cc - rowoff) <= 512u) ? (st[tt][r] + fmv[r]) : -1e30f;
                unsigned short p = f2bf(__builtin_amdgcn_exp2f(arg));
                pb[tt * 4 + r] = p;
                sum += bf2f(p);
            }
        }

        // ---- PV: 2 key-groups of 32; A = V^T[dd][key] from LDS, B = packed P ----
        #pragma unroll
        for (int u = 0; u < 2; ++u) {
            union { unsigned int uu[4]; short8 s8; } pf;
            pf.uu[0] = (unsigned int)pb[8 * u + 0] | ((unsigned int)pb[8 * u + 1] << 16);
            pf.uu[1] = (unsigned int)pb[8 * u + 2] | ((unsigned int)pb[8 * u + 3] << 16);
            pf.uu[2] = (unsigned int)pb[8 * u + 4] | ((unsigned int)pb[8 * u + 5] << 16);
            pf.uu[3] = (unsigned int)pb[8 * u + 6] | ((unsigned int)pb[8 * u + 7] << 16);
            const unsigned short* vp0 = Vb + l16 * 72 + u * 32 + quad * 4;
            short4v v00 = *(const short4v*)(vp0);
            short4v v01 = *(const short4v*)(vp0 + 16);
            acc0 = __builtin_amdgcn_mfma_f32_16x16x32_bf16(cat8(v00, v01), pf.s8, acc0, 0, 0, 0);
            const unsigned short* vp1 = vp0 + 16 * 72;
            short4v v10 = *(const short4v*)(vp1);
            short4v v11 = *(const short4v*)(vp1 + 16);
            acc1 = __builtin_amdgcn_mfma_f32_16x16x32_bf16(cat8(v10, v11), pf.s8, acc1, 0, 0, 0);
            const unsigned short* vp2 = vp0 + 32 * 72;
            short4v v20 = *(const short4v*)(vp2);
            short4v v21 = *(const short4v*)(vp2 + 16);
            acc2 = __builtin_amdgcn_mfma_f32_16x16x32_bf16(cat8(v20, v21), pf.s8, acc2, 0, 0, 0);
            const unsigned short* vp3 = vp0 + 48 * 72;
            short4v v30 = *(const short4v*)(vp3);
            short4v v31 = *(const short4v*)(vp3 + 16);
            acc3 = __builtin_amdgcn_mfma_f32_16x16x32_bf16(cat8(v30, v31), pf.s8, acc3, 0, 0, 0);
        }

        // ---- stage chunk c+1 (other buffer; barrier-separated: race-free) ----
        if (c < 8) {
            *(short8*)(&Ksh[(c + 1) & 1][kr0 * 72 + kc0]) = kA;
            *(short8*)(&Ksh[(c + 1) & 1][kr1 * 72 + kc1]) = kB;
            *(short8*)(&Vsh[(c + 1) & 1][kr0 * 72 + kc0]) = vA;
            *(short8*)(&Vsh[(c + 1) & 1][kr1 * 72 + kc1]) = vB;
            if (c < 7) {
                int base = jw + 64 * (c + 2);
                int a0i = min(max(base + kr0, 0), SEQ - 1);
                int a1i = min(max(base + kr1, 0), SEQ - 1);
                kA = *(const short8*)(kh + (size_t)a0i * HD + kc0);
                kB = *(const short8*)(kh + (size_t)a1i * HD + kc1);
                int b0i = min(max(base + kc0, 0), SEQ - 8);
                int b1i = min(max(base + kc1, 0), SEQ - 8);
                vA = *(const short8*)(vh + (size_t)kr0 * SEQ + b0i);
                vB = *(const short8*)(vh + (size_t)kr1 * SEQ + b1i);
            }
        }
    }

    // ---- row-sum across quads (lanes sharing l16), normalize, write O^T ----
    sum += __shfl_xor(sum, 16);
    sum += __shfl_xor(sum, 32);
    float rinv = imask[row_g] ? 0.f : __builtin_amdgcn_rcpf(sum);

    float* ob = out + (size_t)row_g * EMB + h * HD + quad * 4;
    f32x4 o;
    #pragma unroll
    for (int r = 0; r < 4; ++r) o[r] = acc0[r] * rinv;
    *(f32x4*)(ob) = o;
    #pragma unroll
    for (int r = 0; r < 4; ++r) o[r] = acc1[r] * rinv;
    *(f32x4*)(ob + 16) = o;
    #pragma unroll
    for (int r = 0; r < 4; ++r) o[r] = acc2[r] * rinv;
    *(f32x4*)(ob + 32) = o;
    #pragma unroll
    for (int r = 0; r < 4; ++r) o[r] = acc3[r] * rinv;
    *(f32x4*)(ob + 48) = o;
}

extern "C" void kernel_launch(void* const* d_in, const int* in_sizes, int n_in,
                              void* d_out, int out_size, void* d_ws, size_t ws_size,
                              hipStream_t stream) {
    (void)in_sizes; (void)n_in; (void)out_size; (void)ws_size;
    const float* hid = (const float*)d_in[0];
    const float* am  = (const float*)d_in[1];
    const unsigned char* im = (const unsigned char*)d_in[2];
    const float* Wq = (const float*)d_in[3];
    const float* bq = (const float*)d_in[4];
    const float* Wk = (const float*)d_in[5];
    const float* bk = (const float*)d_in[6];
    const float* Wv = (const float*)d_in[7];
    const float* bv = (const float*)d_in[8];
    float* out = (float*)d_out;

    unsigned short* ws = (unsigned short*)d_ws;
    unsigned short* q_ws = ws;
    unsigned short* k_ws = ws + (size_t)NH * SEQ * HD;
    unsigned short* v_ws = ws + 2 * (size_t)NH * SEQ * HD;
    unsigned short* hidb = (unsigned short*)d_out;   // d_out as scratch (attn overwrites last)
    unsigned short* Wt   = hidb + (size_t)SEQ * EMB;

    prep_kernel<<<dim3(1008), 256, 0, stream>>>(hid, Wq, Wk, Wv, hidb, Wt);
    gemm_kernel<<<dim3(64, 18), 256, 0, stream>>>(hidb, Wt, bq, bk, bv, q_ws, k_ws, v_ws);
    attn_kernel<<<dim3(768), 256, 0, stream>>>(q_ws, k_ws, v_ws, am, im, out);
}